// Round 3
// baseline (413.064 us; speedup 1.0000x reference)
//
#include <hip/hip_runtime.h>

// NCC forces, 256^3 fp32, 5x5x5 zero-padded box window, symmetric gradients.
// Fused single kernel. Per block: 32x8 (x,y) tile marching 32 z-planes.
//  - raw planes: 4-slot LDS ring (40-wide, float4 prefetch 1 plane ahead).
//  - center values + z-gradient taps kept in per-thread register histories
//    (removes the 5th ring slot and most finalize LDS reads).
//  - y-box sums -> field-interleaved LDS ytmp (float2 I/O); x-box + z-window
//    (5-deep register history of xy-sums) + finalize in one phase.
//  - 2 barriers per z-step. LDS 21.75 KB -> 7 blocks/CU resident.

#define DIM 256
#define TX  32
#define TY  8
#define ZCH 32
#define PXA 40   // raw x: gx in [x0-4, x0+36), 16B-aligned float4 chunks
#define PY  12   // raw y: gy in [y0-2, y0+10)
#define YJ  36   // ytmp cols: j -> gx = x0-2+j, j in [0,36)
#define NT  256
#define RS  4
#define SLOT(p) (((p) + 4) & 3)

__global__ __launch_bounds__(NT) void ncc_forces_kernel(
    const float* __restrict__ gI,
    const float* __restrict__ gR,
    float* __restrict__ gOut)
{
    __shared__ __align__(16) float rawI[RS][PY][PXA];   // 7680 B
    __shared__ __align__(16) float rawR[RS][PY][PXA];   // 7680 B
    __shared__ __align__(16) float ytmp[TY][YJ][6];     // 6912 B; [0]=sI [1]=sR [2]=sII [3]=sRR [4]=sIR [5]=pad

    const int t  = threadIdx.x;
    const int tx = t & 31;
    const int ty = t >> 5;
    const int x0 = blockIdx.x * TX;
    const int y0 = blockIdx.y * TY;
    const int z0 = blockIdx.z * ZCH;

    // ---- prefetch role: threads 0..119 load I, 128..247 load R (one float4) ----
    const bool pfI   = (t < 120);
    const bool pfR   = (t >= 128 && t < 248);
    const bool pfAct = pfI || pfR;
    const int  pid   = pfI ? t : (t - 128);
    const int  prow  = pid / 10;
    const int  pcol  = (pid - prow * 10) * 4;
    const int  pgy   = y0 - 2 + prow;
    const int  pgx   = x0 - 4 + pcol;
    const float* pbase = pfI ? gI : gR;
    float*       praw  = pfI ? &rawI[0][0][0] : &rawR[0][0][0];
    const bool   pxyOk = ((unsigned)pgy < DIM) && ((unsigned)pgx < DIM);

    // ---- y-box role: threads 0..143, two adjacent columns each ----
    const bool bAct = (t < 144);
    const int  brow = t / 18;                 // 0..7
    const int  bj   = (t - brow * 18) * 2;    // 0,2,..,34

    float4 pf = make_float4(0.f, 0.f, 0.f, 0.f);

    // ---- prologue: plane z0-2 direct to LDS; plane z0-1 into pf regs ----
    if (pfAct) {
        float4 v = make_float4(0.f, 0.f, 0.f, 0.f);
        const int zp0 = z0 - 2;
        if (zp0 >= 0 && pxyOk)
            v = *(const float4*)(pbase + (((size_t)zp0 * DIM + pgy) * DIM + pgx));
        *(float4*)(praw + (SLOT(z0 - 2) * PY + prow) * PXA + pcol) = v;
        const int zp1 = z0 - 1;
        if (zp1 >= 0 && pxyOk)
            pf = *(const float4*)(pbase + (((size_t)zp1 * DIM + pgy) * DIM + pgx));
    }

    // xy-sum history: planes z-4..z-1 (zeros before chunk start)
    float h[4][5];
    #pragma unroll
    for (int j = 0; j < 4; ++j)
        #pragma unroll
        for (int f = 0; f < 5; ++f) h[j][f] = 0.f;

    // center-value history: planes z-3..z after push at step z
    float hI0 = 0.f, hI1 = 0.f, hI2 = 0.f, hI3 = 0.f;
    float hR0 = 0.f, hR1 = 0.f, hR2 = 0.f, hR3 = 0.f;

    __syncthreads();

    for (int z = z0 - 2; z < z0 + ZCH + 2; ++z) {
        const int sz  = SLOT(z);
        const int szn = SLOT(z + 1);

        // A: commit prefetched plane z+1, then issue load of plane z+2
        if (pfAct) {
            *(float4*)(praw + (szn * PY + prow) * PXA + pcol) = pf;
            float4 v = make_float4(0.f, 0.f, 0.f, 0.f);
            const int zp = z + 2;
            if (zp < DIM && pxyOk)
                v = *(const float4*)(pbase + (((size_t)zp * DIM + pgy) * DIM + pgx));
            pf = v;
        }

        // centers of plane z -> register history (plane z committed last step)
        {
            const float cI = rawI[sz][ty + 2][tx + 4];
            const float cR = rawR[sz][ty + 2][tx + 4];
            hI0 = hI1; hI1 = hI2; hI2 = hI3; hI3 = cI;
            hR0 = hR1; hR1 = hR2; hR2 = hR3; hR3 = cR;
        }

        // B: y-direction 5-wide box sums for plane z (two columns per thread)
        if (bAct) {
            float2 sA  = make_float2(0.f, 0.f), sB  = make_float2(0.f, 0.f);
            float2 sAA = make_float2(0.f, 0.f), sBB = make_float2(0.f, 0.f);
            float2 sAB = make_float2(0.f, 0.f);
            #pragma unroll
            for (int dy = 0; dy < 5; ++dy) {
                const float2 aI = *(const float2*)&rawI[sz][brow + dy][bj + 2];
                const float2 aR = *(const float2*)&rawR[sz][brow + dy][bj + 2];
                sA.x += aI.x;  sA.y += aI.y;
                sB.x += aR.x;  sB.y += aR.y;
                sAA.x = fmaf(aI.x, aI.x, sAA.x); sAA.y = fmaf(aI.y, aI.y, sAA.y);
                sBB.x = fmaf(aR.x, aR.x, sBB.x); sBB.y = fmaf(aR.y, aR.y, sBB.y);
                sAB.x = fmaf(aI.x, aR.x, sAB.x); sAB.y = fmaf(aI.y, aR.y, sAB.y);
            }
            float* y0p = &ytmp[brow][bj][0];
            float* y1p = &ytmp[brow][bj + 1][0];
            *(float2*)(y0p)     = make_float2(sA.x,  sB.x);
            *(float2*)(y0p + 2) = make_float2(sAA.x, sBB.x);
            *(float2*)(y0p + 4) = make_float2(sAB.x, 0.f);
            *(float2*)(y1p)     = make_float2(sA.y,  sB.y);
            *(float2*)(y1p + 2) = make_float2(sAA.y, sBB.y);
            *(float2*)(y1p + 4) = make_float2(sAB.y, 0.f);
        }
        __syncthreads();

        // C: x-direction box sums (window j = tx..tx+4)
        float n0 = 0.f, n1 = 0.f, n2 = 0.f, n3 = 0.f, n4 = 0.f;
        #pragma unroll
        for (int k = 0; k < 5; ++k) {
            const float* yp = &ytmp[ty][tx + k][0];
            const float2 p01 = *(const float2*)yp;
            const float2 p23 = *(const float2*)(yp + 2);
            n0 += p01.x; n1 += p01.y; n2 += p23.x; n3 += p23.y; n4 += yp[4];
        }

        // D: finalize output plane zc = z-2
        const int zc = z - 2;
        if (zc >= z0) {
            const float zs0 = h[0][0] + h[1][0] + h[2][0] + h[3][0] + n0;
            const float zs1 = h[0][1] + h[1][1] + h[2][1] + h[3][1] + n1;
            const float zs2 = h[0][2] + h[1][2] + h[2][2] + h[3][2] + n2;
            const float zs3 = h[0][3] + h[1][3] + h[2][3] + h[3][3] + n3;
            const float zs4 = h[0][4] + h[1][4] + h[2][4] + h[3][4] + n4;

            // faithful to reference: reference_image_mean uses sum_i (their bug)
            const float m     = zs0 * (1.0f / 125.0f);
            const float var_r = zs3 - 2.0f * m * zs1 + 125.0f * m * m;
            const float var_i = zs2 - 2.0f * m * zs0 + 125.0f * m * m;
            const float cross = zs4 - m * zs0 - m * zs1 + 125.0f * m * m;

            // centers & z-gradient from register history: hc = [z-3, z-2, z-1, z]
            const float ic = hI1;
            const float rc = hR1;

            float giz, grz;
            if (zc == 0) {
                giz = hI2 - ic;  grz = hR2 - rc;
            } else if (zc == DIM - 1) {
                giz = ic - hI0;  grz = rc - hR0;
            } else {
                giz = 0.5f * (hI2 - hI0);  grz = 0.5f * (hR2 - hR0);
            }

            const int szc = SLOT(zc);
            const int ly  = ty + 2, lx = tx + 4;

            const int gy = y0 + ty;
            float giy, gry;
            if (gy == 0) {
                giy = rawI[szc][ly + 1][lx] - ic;
                gry = rawR[szc][ly + 1][lx] - rc;
            } else if (gy == DIM - 1) {
                giy = ic - rawI[szc][ly - 1][lx];
                gry = rc - rawR[szc][ly - 1][lx];
            } else {
                giy = 0.5f * (rawI[szc][ly + 1][lx] - rawI[szc][ly - 1][lx]);
                gry = 0.5f * (rawR[szc][ly + 1][lx] - rawR[szc][ly - 1][lx]);
            }

            const int gx = x0 + tx;
            float gix, grx;
            if (gx == 0) {
                gix = rawI[szc][ly][lx + 1] - ic;
                grx = rawR[szc][ly][lx + 1] - rc;
            } else if (gx == DIM - 1) {
                gix = ic - rawI[szc][ly][lx - 1];
                grx = rc - rawR[szc][ly][lx - 1];
            } else {
                gix = 0.5f * (rawI[szc][ly][lx + 1] - rawI[szc][ly][lx - 1]);
                grx = 0.5f * (rawR[szc][ly][lx + 1] - rawR[szc][ly][lx - 1]);
            }

            // fast reciprocals: rel err ~1e-7, absmax budget 2.3e-3
            const float inv_d = __builtin_amdgcn_rcpf(fmaf(var_i, var_r, 1e-6f));
            const float inv_r = __builtin_amdgcn_rcpf(var_r);
            const float factor = 2.0f * cross * inv_d * (ic - cross * inv_r * rc);

            const size_t CS   = (size_t)DIM * DIM * DIM;
            const size_t base = ((size_t)zc * DIM + gy) * DIM + gx;
            gOut[base]          = -factor * 0.5f * (giz + grz);
            gOut[base + CS]     = -factor * 0.5f * (giy + gry);
            gOut[base + 2 * CS] = -factor * 0.5f * (gix + grx);
        }

        // shift xy-sum history
        #pragma unroll
        for (int f = 0; f < 5; ++f) {
            h[0][f] = h[1][f]; h[1][f] = h[2][f]; h[2][f] = h[3][f];
        }
        h[3][0] = n0; h[3][1] = n1; h[3][2] = n2; h[3][3] = n3; h[3][4] = n4;

        __syncthreads();
    }
}

extern "C" void kernel_launch(void* const* d_in, const int* in_sizes, int n_in,
                              void* d_out, int out_size, void* d_ws, size_t ws_size,
                              hipStream_t stream) {
    const float* img = (const float*)d_in[0];  // image
    const float* ref = (const float*)d_in[2];  // reference_image
    float* out = (float*)d_out;

    dim3 grid(DIM / TX, DIM / TY, DIM / ZCH);  // 8 x 32 x 8 = 2048 blocks
    ncc_forces_kernel<<<grid, NT, 0, stream>>>(img, ref, out);
}